// Round 6
// baseline (292.825 us; speedup 1.0000x reference)
//
#include <hip/hip_runtime.h>
#include <stdint.h>

// ---------------------------------------------------------------------------
// GCN 2-layer. R5: gemm reads B-frags straight from global (W is L2-hot;
// LDS 52->17KB so fused fill blocks get occupancy); fill/deg x8 edges/thread;
// zw rows pre-scaled by dinv in gemm epilogue (agg loses per-edge dinv gather);
// agg unroll x8. 9 dispatches.
// ---------------------------------------------------------------------------

typedef __attribute__((ext_vector_type(8))) short short8;
typedef __attribute__((ext_vector_type(4))) float f32x4;

__device__ __forceinline__ uint16_t bf16rne(float f) {
    uint32_t u = __float_as_uint(f);
    uint32_t r = (u + 0x7fffu + ((u >> 16) & 1u)) >> 16;
    return (uint16_t)r;
}
__device__ __forceinline__ float bf_lo(uint32_t v) { return __uint_as_float(v << 16); }
__device__ __forceinline__ float bf_hi(uint32_t v) { return __uint_as_float(v & 0xffff0000u); }

// ---- K1: deg (8 edges/thread) + prep_w ----
__global__ __launch_bounds__(256) void k1(const int* __restrict__ dst, int* __restrict__ degi,
                                          int E, int nbE,
                                          const float* __restrict__ W1, const float* __restrict__ W2,
                                          uint16_t* __restrict__ Wt1, uint16_t* __restrict__ Wt2) {
    int bid = blockIdx.x, t = threadIdx.x;
    if (bid < nbE) {
        int base = bid * 2048 + t;
        int d[8];
#pragma unroll
        for (int k = 0; k < 8; ++k) { int e = base + k * 256; d[k] = (e < E) ? dst[e] : -1; }
#pragma unroll
        for (int k = 0; k < 8; ++k) if (d[k] >= 0) atomicAdd(&degi[d[k]], 1);
    } else {
        int p = (bid - nbE) * 256 + t;   // 0..32767
        const float* W = (p & 16384) ? W2 : W1;
        uint16_t* O = (p & 16384) ? Wt2 : Wt1;
        int rem = p & 16383;
        int kk = rem >> 7, nn = rem & 127;
        O[nn * 128 + kk] = bf16rne(W[rem]);
    }
}

// ---- scanA: local scan + dinv + block sums ----
__global__ __launch_bounds__(1024) void scanA(const int* __restrict__ degi,
                                              float* __restrict__ dinv,
                                              int* __restrict__ row_off,
                                              int* __restrict__ bsum, int n) {
    __shared__ int lds[1024];
    int t = threadIdx.x;
    int base = blockIdx.x * 1024;
    int v = (base + t < n) ? degi[base + t] : 0;
    if (base + t < n) dinv[base + t] = rsqrtf((float)(v + 1));
    lds[t] = v;
    __syncthreads();
    for (int off = 1; off < 1024; off <<= 1) {
        int add = (t >= off) ? lds[t - off] : 0;
        __syncthreads();
        lds[t] += add;
        __syncthreads();
    }
    if (base + t < n) row_off[base + t] = lds[t] - v;
    if (t == 1023) bsum[blockIdx.x] = lds[1023];
}

// ---- scanC: each block wave-scans bsum itself, adds offset (nb <= 64) ----
__global__ __launch_bounds__(1024) void scanC(int* __restrict__ row_off,
                                              int* __restrict__ cursor,
                                              const int* __restrict__ bsum,
                                              int nb, int n) {
    __shared__ int boff_s;
    int t = threadIdx.x;
    if (t < 64) {
        int v = (t < nb) ? bsum[t] : 0;
        int incl = v;
        for (int off = 1; off < 64; off <<= 1) {
            int u = __shfl_up(incl, off, 64);
            if (t >= off) incl += u;
        }
        if (t == (int)blockIdx.x) boff_s = incl - v;
        if (blockIdx.x == 0 && t == nb - 1) row_off[n] = incl;
    }
    __syncthreads();
    int i = blockIdx.x * 1024 + t;
    if (i < n) {
        int ro = row_off[i] + boff_s;
        row_off[i] = ro;
        cursor[i] = ro;
    }
}

// ---- gemm core: A from LDS (wave-private rows), B-frags from global (L2-hot),
//      epilogue pre-scales rows by dinv and stores packed bf16 ----
#define LDW 136
__device__ __forceinline__ void gemm_core(const uint16_t* __restrict__ Wt,
                                          uint16_t* Xl,
                                          const float* __restrict__ dinv,
                                          uint16_t* __restrict__ Y, int nrows,
                                          int row0, int lane, int w) {
    int m = lane & 15, quad = lane >> 4;
    f32x4 acc[8];
#pragma unroll
    for (int i = 0; i < 8; ++i) acc[i] = (f32x4){0.f, 0.f, 0.f, 0.f};
#pragma unroll
    for (int ks = 0; ks < 4; ++ks) {
        short8 a = *(short8*)&Xl[(w * 16 + m) * LDW + ks * 32 + quad * 8];
#pragma unroll
        for (int n0 = 0; n0 < 8; ++n0) {
            short8 b = *(const short8*)&Wt[(n0 * 16 + m) * 128 + ks * 32 + quad * 8];
            acc[n0] = __builtin_amdgcn_mfma_f32_16x16x32_bf16(a, b, acc[n0], 0, 0, 0);
        }
    }
    // scale by dinv[row] in f32 (single rounding), stash bf16 in wave-private rows
    float dv[4];
#pragma unroll
    for (int r = 0; r < 4; ++r) {
        int row = row0 + w * 16 + quad * 4 + r;
        dv[r] = (row < nrows) ? dinv[row] : 0.f;
    }
#pragma unroll
    for (int n0 = 0; n0 < 8; ++n0)
#pragma unroll
        for (int r = 0; r < 4; ++r)
            Xl[(w * 16 + quad * 4 + r) * LDW + n0 * 16 + m] = bf16rne(acc[n0][r] * dv[r]);
    for (int r16 = 0; r16 < 16; ++r16) {
        int row = row0 + w * 16 + r16;
        if (row < nrows) {
            uint32_t v = *(uint32_t*)&Xl[(w * 16 + r16) * LDW + lane * 2];
            ((uint32_t*)Y)[(size_t)row * 64 + lane] = v;
        }
    }
}

// ---- gemm body, f32 input (layer 1) ----
__device__ __forceinline__ void gemm_body_f32(const float* __restrict__ X,
                                              const uint16_t* __restrict__ Wt,
                                              const float* __restrict__ dinv,
                                              uint16_t* __restrict__ Y, int nrows,
                                              uint16_t* Xl, int bid, int t) {
    int lane = t & 63, w = t >> 6;
    int row0 = bid * 64;
    for (int c = t; c < 2048; c += 256) {
        int r = c >> 5, co = (c & 31) * 4;
        float4 v = make_float4(0.f, 0.f, 0.f, 0.f);
        if (row0 + r < nrows) v = *(const float4*)&X[(size_t)(row0 + r) * 128 + co];
        uint32_t lo = (uint32_t)bf16rne(v.x) | ((uint32_t)bf16rne(v.y) << 16);
        uint32_t hi = (uint32_t)bf16rne(v.z) | ((uint32_t)bf16rne(v.w) << 16);
        *(uint2*)&Xl[r * LDW + co] = make_uint2(lo, hi);
    }
    __syncthreads();
    gemm_core(Wt, Xl, dinv, Y, nrows, row0, lane, w);
}

// ---- gemm kernel, bf16 input (layer 2) ----
__global__ __launch_bounds__(256) void gemm_bf(const uint16_t* __restrict__ Xb,
                                               const uint16_t* __restrict__ Wt,
                                               const float* __restrict__ dinv,
                                               uint16_t* __restrict__ Y, int nrows) {
    __shared__ uint16_t Xl[64 * LDW];
    int t = threadIdx.x;
    int lane = t & 63, w = t >> 6;
    int row0 = blockIdx.x * 64;
    for (int c = t; c < 1024; c += 256) {
        int r = c >> 4, co = (c & 15) * 8;
        short8 v = {0, 0, 0, 0, 0, 0, 0, 0};
        if (row0 + r < nrows) v = *(const short8*)&Xb[(size_t)(row0 + r) * 128 + co];
        *(short8*)&Xl[r * LDW + co] = v;
    }
    __syncthreads();
    gemm_core(Wt, Xl, dinv, Y, nrows, row0, lane, w);
}

// ---- fill body: 8 edges/thread, batched phases ----
__device__ __forceinline__ void fill_body(const int* __restrict__ src, const int* __restrict__ dst,
                                          int* __restrict__ cursor, int* __restrict__ col,
                                          int E, int fb, int t) {
    int base = fb * 2048 + t;
    int d[8], s[8], p[8];
#pragma unroll
    for (int k = 0; k < 8; ++k) {
        int e = base + k * 256;
        d[k] = (e < E) ? dst[e] : -1;
        s[k] = (e < E) ? src[e] : 0;
    }
#pragma unroll
    for (int k = 0; k < 8; ++k) if (d[k] >= 0) p[k] = atomicAdd(&cursor[d[k]], 1);
#pragma unroll
    for (int k = 0; k < 8; ++k) if (d[k] >= 0) col[p[k]] = s[k];
}

// ---- K5: gemm1 (+) fill, interleaved ----
__global__ __launch_bounds__(256) void k5(const float* __restrict__ X, const uint16_t* __restrict__ Wt,
                                          const float* __restrict__ dinv,
                                          uint16_t* __restrict__ Y, int nrows, int gemmGrid,
                                          const int* __restrict__ src, const int* __restrict__ dst,
                                          int* __restrict__ cursor, int* __restrict__ col,
                                          int E, int fillGrid) {
    __shared__ uint16_t Xl[64 * LDW];
    int bid = blockIdx.x, t = threadIdx.x;
    int mn = min(gemmGrid, fillGrid);
    int role, idx;
    if (bid < 2 * mn) { role = bid & 1; idx = bid >> 1; }
    else { role = (gemmGrid > fillGrid) ? 0 : 1; idx = bid - 2 * mn + mn; }
    if (role == 0) gemm_body_f32(X, Wt, dinv, Y, nrows, Xl, idx, t);
    else fill_body(src, dst, cursor, col, E, idx, t);
}

// ---- agg + fused pool: 4 waves = 4 nodes per block; zw rows pre-scaled ----
__global__ __launch_bounds__(256) void aggp(const uint32_t* __restrict__ zw,
                                            const float* __restrict__ dinv,
                                            const int* __restrict__ row_off,
                                            const int* __restrict__ col,
                                            const float* __restrict__ bias,
                                            const float* __restrict__ alpha,
                                            const int* __restrict__ batch,
                                            float* __restrict__ gout, int col_off,
                                            uint32_t* __restrict__ z1b,
                                            float* __restrict__ zoutf,
                                            int mode, int n) {
    __shared__ int gsh[4];
    __shared__ float red[4][128];
    int wv = threadIdx.x >> 6;
    int lane = threadIdx.x & 63;
    int node = blockIdx.x * 4 + wv;
    bool valid = node < n;
    int nc = __builtin_amdgcn_readfirstlane(valid ? node : (n - 1));
    int c = lane * 2;
    float di = dinv[nc];
    uint32_t sv = zw[(size_t)nc * 64 + lane];     // pre-scaled di*zw_i = self term
    float ax = bf_lo(sv), ay = bf_hi(sv);
    float bx = 0.f, by = 0.f;
    int e0 = row_off[nc], e1 = row_off[nc + 1];
    int e = e0;
    for (; e + 7 < e1; e += 8) {
        int s0 = col[e],     s1 = col[e + 1], s2 = col[e + 2], s3 = col[e + 3];
        int s4 = col[e + 4], s5 = col[e + 5], s6 = col[e + 6], s7 = col[e + 7];
        uint32_t v0 = zw[(size_t)s0 * 64 + lane];
        uint32_t v1 = zw[(size_t)s1 * 64 + lane];
        uint32_t v2 = zw[(size_t)s2 * 64 + lane];
        uint32_t v3 = zw[(size_t)s3 * 64 + lane];
        uint32_t v4 = zw[(size_t)s4 * 64 + lane];
        uint32_t v5 = zw[(size_t)s5 * 64 + lane];
        uint32_t v6 = zw[(size_t)s6 * 64 + lane];
        uint32_t v7 = zw[(size_t)s7 * 64 + lane];
        ax += bf_lo(v0); ay += bf_hi(v0);
        bx += bf_lo(v1); by += bf_hi(v1);
        ax += bf_lo(v2); ay += bf_hi(v2);
        bx += bf_lo(v3); by += bf_hi(v3);
        ax += bf_lo(v4); ay += bf_hi(v4);
        bx += bf_lo(v5); by += bf_hi(v5);
        ax += bf_lo(v6); ay += bf_hi(v6);
        bx += bf_lo(v7); by += bf_hi(v7);
    }
    for (; e < e1; ++e) {
        int s = col[e];
        uint32_t v = zw[(size_t)s * 64 + lane];
        ax += bf_lo(v); ay += bf_hi(v);
    }
    ax += bx; ay += by;
    float zx = di * ax + bias[c];
    float zy = di * ay + bias[c + 1];
    float px = alpha[c], py = alpha[c + 1];
    zx = zx > 0.f ? zx : px * zx;
    zy = zy > 0.f ? zy : py * zy;

    if (valid) {
        if (mode == 0) {
            uint32_t pk = (uint32_t)bf16rne(zx) | ((uint32_t)bf16rne(zy) << 16);
            z1b[(size_t)nc * 64 + lane] = pk;
        } else {
            ((float2*)zoutf)[(size_t)nc * 64 + lane] = make_float2(zx, zy);
        }
    }

    // fused global_add_pool
    int g = batch[nc];
    float cx = valid ? zx : 0.f, cy = valid ? zy : 0.f;
    if (lane == 0) gsh[wv] = valid ? g : -1 - wv;
    __syncthreads();
    bool uni = (gsh[0] == gsh[1]) && (gsh[1] == gsh[2]) && (gsh[2] == gsh[3]);
    if (uni) {
        red[wv][c] = cx; red[wv][c + 1] = cy;
        __syncthreads();
        if (wv == 0) {
            float sx = red[0][c] + red[1][c] + red[2][c] + red[3][c];
            float sy = red[0][c + 1] + red[1][c + 1] + red[2][c + 1] + red[3][c + 1];
            float* base = &gout[(size_t)g * 256 + col_off];
            atomicAdd(&base[c], sx);
            atomicAdd(&base[c + 1], sy);
        }
    } else if (valid) {
        float* base = &gout[(size_t)g * 256 + col_off];
        atomicAdd(&base[c], cx);
        atomicAdd(&base[c + 1], cy);
    }
}

extern "C" void kernel_launch(void* const* d_in, const int* in_sizes, int n_in,
                              void* d_out, int out_size, void* d_ws, size_t ws_size,
                              hipStream_t stream) {
    const float* x     = (const float*)d_in[0];
    const int*   eidx  = (const int*)d_in[1];
    const int*   batch = (const int*)d_in[2];
    const float* W1    = (const float*)d_in[3];
    const float* b1    = (const float*)d_in[4];
    const float* W2    = (const float*)d_in[5];
    const float* b2    = (const float*)d_in[6];
    const float* alpha = (const float*)d_in[7];

    const int N = in_sizes[2];
    const int E = in_sizes[1] / 2;
    const int G = (out_size - N * 128) / 256;

    const int* src = eidx;
    const int* dst = eidx + E;

    char* ws = (char*)d_ws;
    size_t off = 0;
    auto alloc = [&](size_t bytes) { void* p = ws + off; off = (off + bytes + 255) & ~(size_t)255; return p; };
    int*      degi    = (int*)alloc((size_t)N * 4);
    float*    dinv    = (float*)alloc((size_t)N * 4);
    int*      row_off = (int*)alloc((size_t)(N + 1) * 4);
    int*      cursor  = (int*)alloc((size_t)N * 4);
    int*      bsum    = (int*)alloc(64 * 4);
    int*      col     = (int*)alloc((size_t)E * 4);
    uint32_t* zw      = (uint32_t*)alloc((size_t)N * 128 * 2);
    uint32_t* z1b     = (uint32_t*)alloc((size_t)N * 128 * 2);
    uint16_t* Wt1     = (uint16_t*)alloc(128 * 128 * 2);
    uint16_t* Wt2     = (uint16_t*)alloc(128 * 128 * 2);

    float* z_out = (float*)d_out;
    float* g_out = (float*)d_out + (size_t)N * 128;

    hipMemsetAsync(degi, 0, (size_t)N * sizeof(int), stream);
    hipMemsetAsync(g_out, 0, (size_t)G * 256 * sizeof(float), stream);

    int nbE = (E + 2047) / 2048;           // deg/fill blocks (8 edges/thread)
    int nb  = (N + 1023) / 1024;
    int gemmGrid = (N + 63) / 64;
    int aggGrid  = (N + 3) / 4;

    k1<<<nbE + 128, 256, 0, stream>>>(dst, degi, E, nbE, W1, W2, Wt1, Wt2);
    scanA<<<nb, 1024, 0, stream>>>(degi, dinv, row_off, bsum, N);
    scanC<<<nb, 1024, 0, stream>>>(row_off, cursor, bsum, nb, N);

    k5<<<gemmGrid + nbE, 256, 0, stream>>>(x, Wt1, dinv, (uint16_t*)zw, N, gemmGrid,
                                           src, dst, cursor, col, E, nbE);
    aggp<<<aggGrid, 256, 0, stream>>>(zw, dinv, row_off, col, b1, alpha, batch,
                                      g_out, 0, z1b, nullptr, 0, N);
    gemm_bf<<<gemmGrid, 256, 0, stream>>>((const uint16_t*)z1b, Wt2, dinv, (uint16_t*)zw, N);
    aggp<<<aggGrid, 256, 0, stream>>>(zw, dinv, row_off, col, b2, alpha, batch,
                                      g_out, 128, nullptr, z_out, 1, N);
}

// Round 7
// 274.231 us; speedup vs baseline: 1.0678x; 1.0678x over previous
//
#include <hip/hip_runtime.h>
#include <stdint.h>

// ---------------------------------------------------------------------------
// GCN 2-layer. R6: revert B-from-global (L2 latency killed it). W staged in
// LDS in FRAGMENT-MAJOR order (conflict-free b128, no pad, exactly 32KB);
// A-frags read once from global as bf16 (x pre-converted in k1); epilogue
// reuses Wl after barrier -> 32.8KB LDS, 5 blocks/CU for fused fill.
// ---------------------------------------------------------------------------

typedef __attribute__((ext_vector_type(8))) short short8;
typedef __attribute__((ext_vector_type(4))) float f32x4;

__device__ __forceinline__ uint16_t bf16rne(float f) {
    uint32_t u = __float_as_uint(f);
    uint32_t r = (u + 0x7fffu + ((u >> 16) & 1u)) >> 16;
    return (uint16_t)r;
}
__device__ __forceinline__ float bf_lo(uint32_t v) { return __uint_as_float(v << 16); }
__device__ __forceinline__ float bf_hi(uint32_t v) { return __uint_as_float(v & 0xffff0000u); }

// ---- K1: deg (8 edges/thread) | prep_w (frag-major) | x->bf16 ----
__global__ __launch_bounds__(256) void k1(const int* __restrict__ dst, int* __restrict__ degi,
                                          int E, int nbE,
                                          const float* __restrict__ W1, const float* __restrict__ W2,
                                          uint16_t* __restrict__ Wf1, uint16_t* __restrict__ Wf2,
                                          const float* __restrict__ x, uint16_t* __restrict__ xb,
                                          int N) {
    int bid = blockIdx.x, t = threadIdx.x;
    if (bid < nbE) {
        int base = bid * 2048 + t;
        int d[8];
#pragma unroll
        for (int k = 0; k < 8; ++k) { int e = base + k * 256; d[k] = (e < E) ? dst[e] : -1; }
#pragma unroll
        for (int k = 0; k < 8; ++k) if (d[k] >= 0) atomicAdd(&degi[d[k]], 1);
    } else if (bid < nbE + 16) {
        // frag-major W: Wf[((n0*4+ks)*64+lane)*8 + j] = bf16(W[kk][nn]),
        // nn = n0*16 + (lane&15), kk = ks*32 + (lane>>4)*8 + j
        int tid = (bid - nbE) * 256 + t;        // 0..4095
        const float* W = (tid & 2048) ? W2 : W1;
        uint16_t* O = (tid & 2048) ? Wf2 : Wf1;
        int q16 = tid & 2047;
        int n0ks = q16 >> 6, lane = q16 & 63;
        int n0 = n0ks >> 2, ks = n0ks & 3;
        int m = lane & 15, quad = lane >> 4;
        int nn = n0 * 16 + m;
        int kkb = ks * 32 + quad * 8;
        uint16_t v[8];
#pragma unroll
        for (int j = 0; j < 8; ++j) v[j] = bf16rne(W[(kkb + j) * 128 + nn]);
        *(short8*)&O[q16 * 8] = *(short8*)v;
    } else {
        // x -> bf16 packed, 8 elems/thread
        size_t total = (size_t)N * 128;
        size_t base = (size_t)(bid - nbE - 16) * 2048 + (size_t)t * 8;
        if (base + 8 <= total) {
            float4 v0 = *(const float4*)&x[base];
            float4 v1 = *(const float4*)&x[base + 4];
            uint32_t p[4];
            p[0] = (uint32_t)bf16rne(v0.x) | ((uint32_t)bf16rne(v0.y) << 16);
            p[1] = (uint32_t)bf16rne(v0.z) | ((uint32_t)bf16rne(v0.w) << 16);
            p[2] = (uint32_t)bf16rne(v1.x) | ((uint32_t)bf16rne(v1.y) << 16);
            p[3] = (uint32_t)bf16rne(v1.z) | ((uint32_t)bf16rne(v1.w) << 16);
            *(uint4*)&xb[base] = *(uint4*)p;
        } else {
            for (size_t i = base; i < total; ++i) xb[i] = bf16rne(x[i]);
        }
    }
}

// ---- scanA: local scan + dinv + block sums ----
__global__ __launch_bounds__(1024) void scanA(const int* __restrict__ degi,
                                              float* __restrict__ dinv,
                                              int* __restrict__ row_off,
                                              int* __restrict__ bsum, int n) {
    __shared__ int lds[1024];
    int t = threadIdx.x;
    int base = blockIdx.x * 1024;
    int v = (base + t < n) ? degi[base + t] : 0;
    if (base + t < n) dinv[base + t] = rsqrtf((float)(v + 1));
    lds[t] = v;
    __syncthreads();
    for (int off = 1; off < 1024; off <<= 1) {
        int add = (t >= off) ? lds[t - off] : 0;
        __syncthreads();
        lds[t] += add;
        __syncthreads();
    }
    if (base + t < n) row_off[base + t] = lds[t] - v;
    if (t == 1023) bsum[blockIdx.x] = lds[1023];
}

// ---- scanC: each block wave-scans bsum itself, adds offset (nb <= 64) ----
__global__ __launch_bounds__(1024) void scanC(int* __restrict__ row_off,
                                              int* __restrict__ cursor,
                                              const int* __restrict__ bsum,
                                              int nb, int n) {
    __shared__ int boff_s;
    int t = threadIdx.x;
    if (t < 64) {
        int v = (t < nb) ? bsum[t] : 0;
        int incl = v;
        for (int off = 1; off < 64; off <<= 1) {
            int u = __shfl_up(incl, off, 64);
            if (t >= off) incl += u;
        }
        if (t == (int)blockIdx.x) boff_s = incl - v;
        if (blockIdx.x == 0 && t == nb - 1) row_off[n] = incl;
    }
    __syncthreads();
    int i = blockIdx.x * 1024 + t;
    if (i < n) {
        int ro = row_off[i] + boff_s;
        row_off[i] = ro;
        cursor[i] = ro;
    }
}

// ---- gemm body: A bf16 from global (read-once), W frag-major in LDS (32KB),
//      epilogue reuses Wl; rows pre-scaled by dinv; out packed bf16 ----
__device__ __forceinline__ void gemm_body(const uint16_t* __restrict__ Xb,
                                          const uint16_t* __restrict__ Wf,
                                          const float* __restrict__ dinv,
                                          uint16_t* __restrict__ Y, int nrows,
                                          uint16_t* Wl, int bid, int t) {
    int lane = t & 63, w = t >> 6;
    int row0 = bid * 64;
    // stage Wf (contiguous 32KB, coalesced)
    for (int c = t; c < 2048; c += 256)
        *(short8*)&Wl[c * 8] = *(const short8*)&Wf[c * 8];
    // A frags from global: lane owns row (w*16 + m), 4 chunks of 16B
    int m = lane & 15, quad = lane >> 4;
    int arow = row0 + w * 16 + m;
    bool rowok = arow < nrows;
    const uint16_t* aptr = Xb + (size_t)arow * 128 + quad * 8;
    short8 a[4];
#pragma unroll
    for (int ks = 0; ks < 4; ++ks) {
        short8 z = {0, 0, 0, 0, 0, 0, 0, 0};
        a[ks] = rowok ? *(const short8*)(aptr + ks * 32) : z;
    }
    __syncthreads();

    f32x4 acc[8];
#pragma unroll
    for (int i = 0; i < 8; ++i) acc[i] = (f32x4){0.f, 0.f, 0.f, 0.f};
#pragma unroll
    for (int ks = 0; ks < 4; ++ks)
#pragma unroll
        for (int n0 = 0; n0 < 8; ++n0) {
            short8 b = *(short8*)&Wl[((n0 * 4 + ks) * 64 + lane) * 8];
            acc[n0] = __builtin_amdgcn_mfma_f32_16x16x32_bf16(a[ks], b, acc[n0], 0, 0, 0);
        }
    __syncthreads();  // all waves done reading Wl; reuse it for epilogue

    // C/D layout: col = lane&15 (=m), row = quad*4 + r
    float dv[4];
#pragma unroll
    for (int r = 0; r < 4; ++r) {
        int row = row0 + w * 16 + quad * 4 + r;
        dv[r] = (row < nrows) ? dinv[row] : 0.f;
    }
    uint16_t* Ep = Wl;  // view as [64][136], wave-private rows
#pragma unroll
    for (int n0 = 0; n0 < 8; ++n0)
#pragma unroll
        for (int r = 0; r < 4; ++r)
            Ep[(w * 16 + quad * 4 + r) * 136 + n0 * 16 + m] = bf16rne(acc[n0][r] * dv[r]);
    for (int r16 = 0; r16 < 16; ++r16) {
        int row = row0 + w * 16 + r16;
        if (row < nrows) {
            uint32_t v = *(uint32_t*)&Ep[(w * 16 + r16) * 136 + lane * 2];
            ((uint32_t*)Y)[(size_t)row * 64 + lane] = v;
        }
    }
}

// ---- fill body: 8 edges/thread, batched phases ----
__device__ __forceinline__ void fill_body(const int* __restrict__ src, const int* __restrict__ dst,
                                          int* __restrict__ cursor, int* __restrict__ col,
                                          int E, int fb, int t) {
    int base = fb * 2048 + t;
    int d[8], s[8], p[8];
#pragma unroll
    for (int k = 0; k < 8; ++k) {
        int e = base + k * 256;
        d[k] = (e < E) ? dst[e] : -1;
        s[k] = (e < E) ? src[e] : 0;
    }
#pragma unroll
    for (int k = 0; k < 8; ++k) if (d[k] >= 0) p[k] = atomicAdd(&cursor[d[k]], 1);
#pragma unroll
    for (int k = 0; k < 8; ++k) if (d[k] >= 0) col[p[k]] = s[k];
}

// ---- K5: gemm1 (+) fill, interleaved ----
__global__ __launch_bounds__(256) void k5(const uint16_t* __restrict__ Xb,
                                          const uint16_t* __restrict__ Wf,
                                          const float* __restrict__ dinv,
                                          uint16_t* __restrict__ Y, int nrows, int gemmGrid,
                                          const int* __restrict__ src, const int* __restrict__ dst,
                                          int* __restrict__ cursor, int* __restrict__ col,
                                          int E, int fillGrid) {
    __shared__ uint16_t Wl[16384];
    int bid = blockIdx.x, t = threadIdx.x;
    int mn = min(gemmGrid, fillGrid);
    int role, idx;
    if (bid < 2 * mn) { role = bid & 1; idx = bid >> 1; }
    else { role = (gemmGrid > fillGrid) ? 0 : 1; idx = bid - 2 * mn + mn; }
    if (role == 0) gemm_body(Xb, Wf, dinv, Y, nrows, Wl, idx, t);
    else fill_body(src, dst, cursor, col, E, idx, t);
}

// ---- gemm standalone (layer 2) ----
__global__ __launch_bounds__(256) void gemm2k(const uint16_t* __restrict__ Xb,
                                              const uint16_t* __restrict__ Wf,
                                              const float* __restrict__ dinv,
                                              uint16_t* __restrict__ Y, int nrows) {
    __shared__ uint16_t Wl[16384];
    gemm_body(Xb, Wf, dinv, Y, nrows, Wl, blockIdx.x, threadIdx.x);
}

// ---- agg + fused pool: 4 waves = 4 nodes per block; zw rows pre-scaled ----
__global__ __launch_bounds__(256) void aggp(const uint32_t* __restrict__ zw,
                                            const float* __restrict__ dinv,
                                            const int* __restrict__ row_off,
                                            const int* __restrict__ col,
                                            const float* __restrict__ bias,
                                            const float* __restrict__ alpha,
                                            const int* __restrict__ batch,
                                            float* __restrict__ gout, int col_off,
                                            uint32_t* __restrict__ z1b,
                                            float* __restrict__ zoutf,
                                            int mode, int n) {
    __shared__ int gsh[4];
    __shared__ float red[4][128];
    int wv = threadIdx.x >> 6;
    int lane = threadIdx.x & 63;
    int node = blockIdx.x * 4 + wv;
    bool valid = node < n;
    int nc = __builtin_amdgcn_readfirstlane(valid ? node : (n - 1));
    int c = lane * 2;
    float di = dinv[nc];
    uint32_t sv = zw[(size_t)nc * 64 + lane];
    float ax = bf_lo(sv), ay = bf_hi(sv);
    float bx = 0.f, by = 0.f;
    int e0 = row_off[nc], e1 = row_off[nc + 1];
    int e = e0;
    for (; e + 7 < e1; e += 8) {
        int s0 = col[e],     s1 = col[e + 1], s2 = col[e + 2], s3 = col[e + 3];
        int s4 = col[e + 4], s5 = col[e + 5], s6 = col[e + 6], s7 = col[e + 7];
        uint32_t v0 = zw[(size_t)s0 * 64 + lane];
        uint32_t v1 = zw[(size_t)s1 * 64 + lane];
        uint32_t v2 = zw[(size_t)s2 * 64 + lane];
        uint32_t v3 = zw[(size_t)s3 * 64 + lane];
        uint32_t v4 = zw[(size_t)s4 * 64 + lane];
        uint32_t v5 = zw[(size_t)s5 * 64 + lane];
        uint32_t v6 = zw[(size_t)s6 * 64 + lane];
        uint32_t v7 = zw[(size_t)s7 * 64 + lane];
        ax += bf_lo(v0); ay += bf_hi(v0);
        bx += bf_lo(v1); by += bf_hi(v1);
        ax += bf_lo(v2); ay += bf_hi(v2);
        bx += bf_lo(v3); by += bf_hi(v3);
        ax += bf_lo(v4); ay += bf_hi(v4);
        bx += bf_lo(v5); by += bf_hi(v5);
        ax += bf_lo(v6); ay += bf_hi(v6);
        bx += bf_lo(v7); by += bf_hi(v7);
    }
    for (; e < e1; ++e) {
        int s = col[e];
        uint32_t v = zw[(size_t)s * 64 + lane];
        ax += bf_lo(v); ay += bf_hi(v);
    }
    ax += bx; ay += by;
    float zx = di * ax + bias[c];
    float zy = di * ay + bias[c + 1];
    float px = alpha[c], py = alpha[c + 1];
    zx = zx > 0.f ? zx : px * zx;
    zy = zy > 0.f ? zy : py * zy;

    if (valid) {
        if (mode == 0) {
            uint32_t pk = (uint32_t)bf16rne(zx) | ((uint32_t)bf16rne(zy) << 16);
            z1b[(size_t)nc * 64 + lane] = pk;
        } else {
            ((float2*)zoutf)[(size_t)nc * 64 + lane] = make_float2(zx, zy);
        }
    }

    int g = batch[nc];
    float cx = valid ? zx : 0.f, cy = valid ? zy : 0.f;
    if (lane == 0) gsh[wv] = valid ? g : -1 - wv;
    __syncthreads();
    bool uni = (gsh[0] == gsh[1]) && (gsh[1] == gsh[2]) && (gsh[2] == gsh[3]);
    if (uni) {
        red[wv][c] = cx; red[wv][c + 1] = cy;
        __syncthreads();
        if (wv == 0) {
            float sx = red[0][c] + red[1][c] + red[2][c] + red[3][c];
            float sy = red[0][c + 1] + red[1][c + 1] + red[2][c + 1] + red[3][c + 1];
            float* base = &gout[(size_t)g * 256 + col_off];
            atomicAdd(&base[c], sx);
            atomicAdd(&base[c + 1], sy);
        }
    } else if (valid) {
        float* base = &gout[(size_t)g * 256 + col_off];
        atomicAdd(&base[c], cx);
        atomicAdd(&base[c + 1], cy);
    }
}

extern "C" void kernel_launch(void* const* d_in, const int* in_sizes, int n_in,
                              void* d_out, int out_size, void* d_ws, size_t ws_size,
                              hipStream_t stream) {
    const float* x     = (const float*)d_in[0];
    const int*   eidx  = (const int*)d_in[1];
    const int*   batch = (const int*)d_in[2];
    const float* W1    = (const float*)d_in[3];
    const float* b1    = (const float*)d_in[4];
    const float* W2    = (const float*)d_in[5];
    const float* b2    = (const float*)d_in[6];
    const float* alpha = (const float*)d_in[7];

    const int N = in_sizes[2];
    const int E = in_sizes[1] / 2;
    const int G = (out_size - N * 128) / 256;

    const int* src = eidx;
    const int* dst = eidx + E;

    char* ws = (char*)d_ws;
    size_t off = 0;
    auto alloc = [&](size_t bytes) { void* p = ws + off; off = (off + bytes + 255) & ~(size_t)255; return p; };
    int*      degi    = (int*)alloc((size_t)N * 4);
    float*    dinv    = (float*)alloc((size_t)N * 4);
    int*      row_off = (int*)alloc((size_t)(N + 1) * 4);
    int*      cursor  = (int*)alloc((size_t)N * 4);
    int*      bsum    = (int*)alloc(64 * 4);
    int*      col     = (int*)alloc((size_t)E * 4);
    uint32_t* zw      = (uint32_t*)alloc((size_t)N * 128 * 2);
    uint32_t* z1b     = (uint32_t*)alloc((size_t)N * 128 * 2);
    uint16_t* xb      = (uint16_t*)alloc((size_t)N * 128 * 2);
    uint16_t* Wf1     = (uint16_t*)alloc(128 * 128 * 2);
    uint16_t* Wf2     = (uint16_t*)alloc(128 * 128 * 2);

    float* z_out = (float*)d_out;
    float* g_out = (float*)d_out + (size_t)N * 128;

    hipMemsetAsync(degi, 0, (size_t)N * sizeof(int), stream);
    hipMemsetAsync(g_out, 0, (size_t)G * 256 * sizeof(float), stream);

    int nbE = (E + 2047) / 2048;                         // deg/fill blocks (x8)
    int nbX = (int)(((size_t)N * 128 + 2047) / 2048);    // x->bf16 blocks
    int nb  = (N + 1023) / 1024;
    int gemmGrid = (N + 63) / 64;
    int aggGrid  = (N + 3) / 4;

    k1<<<nbE + 16 + nbX, 256, 0, stream>>>(dst, degi, E, nbE, W1, W2, Wf1, Wf2, x, xb, N);
    scanA<<<nb, 1024, 0, stream>>>(degi, dinv, row_off, bsum, N);
    scanC<<<nb, 1024, 0, stream>>>(row_off, cursor, bsum, nb, N);

    k5<<<gemmGrid + nbE, 256, 0, stream>>>(xb, Wf1, dinv, (uint16_t*)zw, N, gemmGrid,
                                           src, dst, cursor, col, E, nbE);
    aggp<<<aggGrid, 256, 0, stream>>>(zw, dinv, row_off, col, b1, alpha, batch,
                                      g_out, 0, z1b, nullptr, 0, N);
    gemm2k<<<gemmGrid, 256, 0, stream>>>((const uint16_t*)z1b, Wf2, dinv, (uint16_t*)zw, N);
    aggp<<<aggGrid, 256, 0, stream>>>(zw, dinv, row_off, col, b2, alpha, batch,
                                      g_out, 128, nullptr, z_out, 1, N);
}